// Round 11
// baseline (141.139 us; speedup 1.0000x reference)
//
#include <hip/hip_runtime.h>
#include <hip/hip_bf16.h>
#include <cstdint>

#define D_   256
#define E_   4096
#define NN_  2048

typedef float f32x4_t __attribute__((ext_vector_type(4)));
typedef short bf16x8_t __attribute__((ext_vector_type(8)));

__device__ inline short f2bf(float f) {
    union { float fv; unsigned u; } v; v.fv = f;
    unsigned r = v.u + 0x7fffu + ((v.u >> 16) & 1u);
    return (short)(r >> 16);
}

__device__ inline unsigned cvtpk_bf16(float lo, float hi) {
    unsigned r;
    asm("v_cvt_pk_bf16_f32 %0, %1, %2" : "=v"(r) : "v"(lo), "v"(hi));
    return r;
}

// ---------------------------------------------------------------------------
// bf16 MFMA GEMM (validated r7/r8/r10): C = epi(A @ Bm^T + bias), inline
// f32->bf16 staging, 64x64 tile, 4 waves, BK=32, dbuf, 1 barrier per K-step.
// ---------------------------------------------------------------------------
template<int ACT, bool GATHER, bool SCATTER, bool HASADD, bool OBF16>
__global__ __launch_bounds__(256)
void mgemm_k(const float* __restrict__ A, const float* __restrict__ Bm,
             const float* __restrict__ bias, const float* __restrict__ addsrc,
             float* __restrict__ C, int M, int N, int K,
             const int* __restrict__ ei0, const int* __restrict__ ei1,
             const float* __restrict__ x, const float* __restrict__ eattr,
             float qsc)
{
    __shared__ char lds[16384];
    const int tid = threadIdx.x;
    const int w = tid >> 6, l = tid & 63;
    const int g = l >> 4, ln = l & 15;
    const int wr = w >> 1, wc = w & 1;
    const int m0 = blockIdx.x * 64, n0 = blockIdx.y * 64;

    const int srow = tid >> 2;
    const int sck  = (tid & 3) * 8;
    const int sswz = (srow & 7) << 4;
    int gi1 = 0, gi0 = 0;
    if (GATHER) { gi1 = ei1[m0 + srow]; gi0 = ei0[m0 + srow]; }

    f32x4_t acc[2][2];
    #pragma unroll
    for (int m = 0; m < 2; m++)
        #pragma unroll
        for (int n = 0; n < 2; n++)
            acc[m][n] = f32x4_t{0.f, 0.f, 0.f, 0.f};

    const int nt = K >> 5;
    float4 ga0, ga1, gb0, gb1;

    auto loadG = [&](int kk) {
        const int cb = kk + sck;
        const float* src;
        if (GATHER) {
            if (cb < 256)      src = x + (size_t)gi1 * 256 + cb;
            else if (cb < 512) src = x + (size_t)gi0 * 256 + (cb - 256);
            else               src = eattr + (size_t)(m0 + srow) * 256 + (cb - 512);
        } else {
            src = A + (size_t)(m0 + srow) * K + cb;
        }
        ga0 = *(const float4*)src;
        ga1 = *(const float4*)(src + 4);
        const float* bsrc = Bm + (size_t)(n0 + srow) * K + cb;
        gb0 = *(const float4*)bsrc;
        gb1 = *(const float4*)(bsrc + 4);
    };
    auto writeS = [&](int buf) {
        uint4 pa, pb;
        pa.x = cvtpk_bf16(ga0.x, ga0.y); pa.y = cvtpk_bf16(ga0.z, ga0.w);
        pa.z = cvtpk_bf16(ga1.x, ga1.y); pa.w = cvtpk_bf16(ga1.z, ga1.w);
        pb.x = cvtpk_bf16(gb0.x, gb0.y); pb.y = cvtpk_bf16(gb0.z, gb0.w);
        pb.z = cvtpk_bf16(gb1.x, gb1.y); pb.w = cvtpk_bf16(gb1.z, gb1.w);
        const int off = (srow*64 + sck*2) ^ sswz;
        *(uint4*)(lds + buf*4096 + off) = pa;
        *(uint4*)(lds + 8192 + buf*4096 + off) = pb;
    };

    loadG(0);
    writeS(0);
    __syncthreads();
    int cur = 0;
    for (int t = 0; t < nt; ++t) {
        if (t + 1 < nt) loadG((t + 1) << 5);
        bf16x8_t af[2], bfr[2];
        #pragma unroll
        for (int m = 0; m < 2; m++) {
            const int row = wr*32 + m*16 + ln;
            af[m] = *(const bf16x8_t*)(lds + cur*4096 + ((row*64 + g*16) ^ ((row&7)<<4)));
        }
        #pragma unroll
        for (int n = 0; n < 2; n++) {
            const int row = wc*32 + n*16 + ln;
            bfr[n] = *(const bf16x8_t*)(lds + 8192 + cur*4096 + ((row*64 + g*16) ^ ((row&7)<<4)));
        }
        #pragma unroll
        for (int m = 0; m < 2; m++)
            #pragma unroll
            for (int n = 0; n < 2; n++)
                acc[m][n] = __builtin_amdgcn_mfma_f32_16x16x32_bf16(af[m], bfr[n], acc[m][n], 0, 0, 0);
        if (t + 1 < nt) writeS(cur ^ 1);
        __syncthreads();
        cur ^= 1;
    }

    #pragma unroll
    for (int m = 0; m < 2; m++) {
        #pragma unroll
        for (int n = 0; n < 2; n++) {
            const int col = n0 + wc*32 + n*16 + ln;
            const float bv = bias[col];
            #pragma unroll
            for (int r = 0; r < 4; r++) {
                const int row = m0 + wr*32 + m*16 + g*4 + r;
                float v = acc[m][n][r] + bv;
                if (ACT == 1) v = v > 0.f ? v : 0.2f * v;
                if (HASADD) v += addsrc[(size_t)row * N + col];
                if (SCATTER) {
                    atomicAdd(&C[(size_t)ei1[row] * 256 + col], v);
                } else if (OBF16) {
                    ((short*)C)[(size_t)row * N + col] = f2bf((col < 256) ? v * qsc : v);
                } else {
                    C[(size_t)row * N + col] = v;
                }
            }
        }
    }
}

// ---------------------------------------------------------------------------
// Fused GEMM + LayerNorm (full-row): out = LN(A @ Bm^T + bias + addsrc).
// A [M,256] f32, Bm [256,256] f32 (Linear weight layout), addsrc may == A
// (residual). Block = 64 rows x 256 cols; 4 waves, each 16 rows x 256 cols
// (16 MFMA frags) -> LN per row is wave-local (shfl over 16 lanes).
// LDS: A dbuf 2x4KB @0, B dbuf 2x16KB @8192, params @40960 (bias,g,b).
// ---------------------------------------------------------------------------
__global__ __launch_bounds__(256)
void rgln_k(const float* __restrict__ A, const float* __restrict__ Bm,
            const float* __restrict__ bias, const float* __restrict__ addsrc,
            const float* __restrict__ lng, const float* __restrict__ lnb,
            float* __restrict__ out)
{
    __shared__ char lds[44032];
    const int tid = threadIdx.x;
    const int w = tid >> 6, l = tid & 63;
    const int g = l >> 4, ln = l & 15;
    const int m0 = blockIdx.x * 64;

    float* pb   = (float*)(lds + 40960);
    float* pg   = pb + 256;
    float* pbet = pg + 256;
    pb[tid] = bias[tid];
    pg[tid] = lng[tid];
    pbet[tid] = lnb[tid];

    const int srow = tid >> 2;          // A staging: row, 8-float chunk
    const int sck  = (tid & 3) * 8;
    const int aswz = (srow & 7) << 4;
    const int bswz = (tid & 7) << 4;    // B staging: row = tid (256 N-rows)

    f32x4_t acc[16];
    #pragma unroll
    for (int n = 0; n < 16; n++) acc[n] = f32x4_t{0.f,0.f,0.f,0.f};

    float4 ga0, ga1, gb[8];
    auto loadG = [&](int kk) {
        const float* asrc = A + (size_t)(m0 + srow) * 256 + kk + sck;
        ga0 = *(const float4*)asrc;
        ga1 = *(const float4*)(asrc + 4);
        const float* bsrc = Bm + (size_t)tid * 256 + kk;
        #pragma unroll
        for (int q = 0; q < 8; q++) gb[q] = *(const float4*)(bsrc + q*4);
    };
    auto writeS = [&](int buf) {
        uint4 pa;
        pa.x = cvtpk_bf16(ga0.x, ga0.y); pa.y = cvtpk_bf16(ga0.z, ga0.w);
        pa.z = cvtpk_bf16(ga1.x, ga1.y); pa.w = cvtpk_bf16(ga1.z, ga1.w);
        *(uint4*)(lds + buf*4096 + ((srow*64 + sck*2) ^ aswz)) = pa;
        #pragma unroll
        for (int q = 0; q < 4; q++) {
            uint4 pbv;
            pbv.x = cvtpk_bf16(gb[q*2].x, gb[q*2].y);
            pbv.y = cvtpk_bf16(gb[q*2].z, gb[q*2].w);
            pbv.z = cvtpk_bf16(gb[q*2+1].x, gb[q*2+1].y);
            pbv.w = cvtpk_bf16(gb[q*2+1].z, gb[q*2+1].w);
            *(uint4*)(lds + 8192 + buf*16384 + ((tid*64 + q*16) ^ bswz)) = pbv;
        }
    };

    loadG(0);
    writeS(0);
    __syncthreads();
    int cur = 0;
    for (int t = 0; t < 8; ++t) {
        if (t < 7) loadG((t + 1) << 5);
        const int arow = w*16 + ln;
        const bf16x8_t af = *(const bf16x8_t*)(lds + cur*4096 + ((arow*64 + g*16) ^ ((arow&7)<<4)));
        #pragma unroll
        for (int n = 0; n < 16; n++) {
            const int brow = n*16 + ln;
            const bf16x8_t bf = *(const bf16x8_t*)(lds + 8192 + cur*16384 + ((brow*64 + g*16) ^ ((brow&7)<<4)));
            acc[n] = __builtin_amdgcn_mfma_f32_16x16x32_bf16(af, bf, acc[n], 0, 0, 0);
        }
        if (t < 7) writeS(cur ^ 1);
        __syncthreads();
        cur ^= 1;
    }

    // epilogue: bias + addsrc, then per-row LayerNorm (wave-local)
    #pragma unroll
    for (int r = 0; r < 4; r++) {
        const int grow = m0 + w*16 + g*4 + r;
        float v[16];
        float s1 = 0.f, s2 = 0.f;
        #pragma unroll
        for (int n = 0; n < 16; n++) {
            const int col = n*16 + ln;
            float vv = acc[n][r] + pb[col] + addsrc[(size_t)grow * 256 + col];
            v[n] = vv;
            s1 += vv;
            s2 += vv * vv;
        }
        #pragma unroll
        for (int off = 1; off < 16; off <<= 1) {
            s1 += __shfl_xor(s1, off);
            s2 += __shfl_xor(s2, off);
        }
        const float mu  = s1 * (1.0f / 256.0f);
        const float var = s2 * (1.0f / 256.0f) - mu * mu;
        const float rs  = rsqrtf(var + 1e-5f);
        #pragma unroll
        for (int n = 0; n < 16; n++) {
            const int col = n*16 + ln;
            out[(size_t)grow * 256 + col] = (v[n] - mu) * rs * pg[col] + pbet[col];
        }
    }
}

// ---------------------------------------------------------------------------
// Prep: mask bit-pack (int32 0/1 layout, established r1->r2 A/B) + aggr zero
// + root transpose, one kernel. Blocks 0..2047: pack+zero; 2048..2063: rootT.
// ---------------------------------------------------------------------------
__global__ __launch_bounds__(256)
void prep_k(const int* __restrict__ mraw, unsigned int* __restrict__ pm,
            const float* __restrict__ root, float* __restrict__ rootT,
            float* __restrict__ aggr)
{
    __shared__ float T[64][65];
    const int bid = blockIdx.x;
    if (bid < 2048) {
        const int t = bid * 256 + threadIdx.x;   // 0 .. 524287
        aggr[t] = 0.f;
        const int row = t >> 7, wb = t & 127;
        unsigned int bits = 0;
        const uint4* p = (const uint4*)(mraw + (size_t)row * 4096 + wb * 32);
        #pragma unroll
        for (int g = 0; g < 8; g++) {
            const uint4 v = p[g];
            if (v.x) bits |= 1u << (g*4+0);
            if (v.y) bits |= 1u << (g*4+1);
            if (v.z) bits |= 1u << (g*4+2);
            if (v.w) bits |= 1u << (g*4+3);
        }
        pm[t] = bits;
    } else {
        const int bt = bid - 2048;
        const int m0 = (bt >> 2) * 64, n0 = (bt & 3) * 64;
        const int r = threadIdx.x >> 6, c = threadIdx.x & 63;
        #pragma unroll
        for (int i = 0; i < 16; i++)
            T[r + i*4][c] = root[(size_t)(m0 + r + i*4) * 256 + n0 + c];
        __syncthreads();
        #pragma unroll
        for (int i = 0; i < 16; i++)
            rootT[(size_t)(n0 + r + i*4) * 256 + m0 + c] = T[c][r + i*4];
    }
}

// ---------------------------------------------------------------------------
// V pre-transpose: vt[head][d=32][key=4096] bf16 from qkv V-part.
// ---------------------------------------------------------------------------
__global__ __launch_bounds__(256)
void vtrans_k(const short* __restrict__ qkvb, short* __restrict__ vt)
{
    __shared__ short Ts[64][40];
    const int head = blockIdx.x >> 6;
    const int k0 = (blockIdx.x & 63) * 64;
    const int tid = threadIdx.x;
    const int skey = tid >> 2, sc = tid & 3;
    const bf16x8_t v = *(const bf16x8_t*)(qkvb + (size_t)(k0 + skey)*768 + 512 + head*32 + sc*8);
    *(bf16x8_t*)(&Ts[skey][sc*8]) = v;
    __syncthreads();
    const int sd = tid >> 3, skc = tid & 7;
    short outv[8];
    #pragma unroll
    for (int j = 0; j < 8; j++) outv[j] = Ts[skc*8 + j][sd];
    *(bf16x8_t*)(vt + (size_t)head*131072 + (size_t)sd*4096 + k0 + skc*8) = *(bf16x8_t*)outv;
}

// ---------------------------------------------------------------------------
// MFMA bf16 flash attention (round-8 validated structure, 60.2 us, FETCH
// 18.5 MB): swapped QK^T + fixed-shift softmax + in-block split-K x2 strided;
// 512 thr = 2 key-groups x 4 q-waves; dbuf K/V; additive merge. + setprio
// around MFMA clusters (T5). DO NOT widen split-K: x4 (r9) and range-split
// (r5) both collapsed L2 (FETCH 287/404 MB) via cross-block stream drift.
// ---------------------------------------------------------------------------
__global__ __launch_bounds__(512, 4)
void attn_k(const short* __restrict__ qkvb, const short* __restrict__ vt,
            const unsigned int* __restrict__ pmask, float* __restrict__ o)
{
    __shared__ char lds[49152];
    const int tid = threadIdx.x;
    const int w2 = tid >> 6, l = tid & 63;
    const int g = l >> 4, ln = l & 15;
    const int gi = w2 >> 2, wq = w2 & 3;
    const int head = blockIdx.x >> 6;
    const int q0 = (blockIdx.x & 63) * 64;
    const int qa = q0 + wq * 16 + ln;

    const bf16x8_t qf = *(const bf16x8_t*)(qkvb + (size_t)qa*768 + head*32 + g*8);

    f32x4_t oT0 = {0.f,0.f,0.f,0.f};
    f32x4_t oT1 = {0.f,0.f,0.f,0.f};
    float lsum = 0.f;

    const int st = tid & 255;
    const int skey = st >> 2, sc = st & 3;
    const int sd = st >> 3, skc = st & 7;
    const short* kgp = qkvb + 256 + head*32 + sc*8;
    const short* vgp = vt + (size_t)head*131072 + (size_t)sd*4096 + skc*8;
    char* Kg = lds + gi*8192;
    char* Vg = lds + 16384 + gi*8192;
    char* Pw = lds + 32768 + w2*2048;
    const unsigned int* mrow = pmask + (size_t)qa*128;
    const int kswz = (skey & 7) << 4, vswz = (sd & 7) << 4;
    const int pswz = (ln & 7) << 4;

    {   // stage this group's first tile (tt = gi) -> buf 0
        const int k0 = gi * 64;
        const bf16x8_t kv = *(const bf16x8_t*)(kgp + (size_t)(k0 + skey)*768);
        *(bf16x8_t*)(Kg + ((skey*64 + sc*16) ^ kswz)) = kv;
        const bf16x8_t vv = *(const bf16x8_t*)(vgp + k0);
        *(bf16x8_t*)(Vg + ((sd*128 + skc*16) ^ vswz)) = vv;
    }

    for (int i = 0; i < 32; ++i) {
        __syncthreads();
        const int cur = i & 1;
        const int tt = 2*i + gi;
        if (i < 31) {   // prefetch this group's next tile (tt+2)
            const int k0n = (tt + 2) * 64;
            const bf16x8_t kv = *(const bf16x8_t*)(kgp + (size_t)(k0n + skey)*768);
            *(bf16x8_t*)(Kg + (cur^1)*4096 + ((skey*64 + sc*16) ^ kswz)) = kv;
            const bf16x8_t vv = *(const bf16x8_t*)(vgp + k0n);
            *(bf16x8_t*)(Vg + (cur^1)*4096 + ((sd*128 + skc*16) ^ vswz)) = vv;
        }
        char* Kb = Kg + cur*4096;
        char* Vb = Vg + cur*4096;

        // S^T = mfma(K, Q): col=q=ln, rows = keys kt*16+g*4+r
        f32x4_t s[4];
        __builtin_amdgcn_s_setprio(1);
        #pragma unroll
        for (int kt = 0; kt < 4; kt++) {
            const int key = kt*16 + ln;
            const bf16x8_t kf = *(const bf16x8_t*)(Kb + ((key*64 + g*16) ^ ((key & 7) << 4)));
            f32x4_t z = {0.f,0.f,0.f,0.f};
            s[kt] = __builtin_amdgcn_mfma_f32_16x16x32_bf16(kf, qf, z, 0, 0, 0);
        }
        __builtin_amdgcn_s_setprio(0);

        // fixed-shift masked exp; lsum; pack P -> LDS
        const uint2 mw = *(const uint2*)(mrow + tt*2);
        #pragma unroll
        for (int kt = 0; kt < 4; kt++) {
            const unsigned word = (kt < 2) ? mw.x : mw.y;
            float p[4];
            #pragma unroll
            for (int r = 0; r < 4; r++) {
                const float e = __expf(s[kt][r] - 12.0f);
                p[r] = ((word >> ((kt & 1)*16 + g*4 + r)) & 1u) ? e : 0.f;
            }
            lsum += (p[0] + p[1]) + (p[2] + p[3]);
            uint2 pk;
            pk.x = cvtpk_bf16(p[0], p[1]);
            pk.y = cvtpk_bf16(p[2], p[3]);
            *(uint2*)(Pw + ((ln*128 + kt*32 + g*8) ^ pswz)) = pk;
        }

        // PV: O^T += Vt . P
        __builtin_amdgcn_s_setprio(1);
        #pragma unroll
        for (int kh = 0; kh < 2; kh++) {
            const bf16x8_t pf = *(const bf16x8_t*)(Pw + ((ln*128 + kh*64 + g*16) ^ pswz));
            const bf16x8_t vf0 = *(const bf16x8_t*)(Vb + ((ln*128 + kh*64 + g*16) ^ pswz));
            const bf16x8_t vf1 = *(const bf16x8_t*)(Vb + (((16+ln)*128 + kh*64 + g*16) ^ pswz));
            oT0 = __builtin_amdgcn_mfma_f32_16x16x32_bf16(vf0, pf, oT0, 0, 0, 0);
            oT1 = __builtin_amdgcn_mfma_f32_16x16x32_bf16(vf1, pf, oT1, 0, 0, 0);
        }
        __builtin_amdgcn_s_setprio(0);
    }

    // ---- additive merge of the two key-group partials ----
    __syncthreads();
    *(f32x4_t*)(lds + w2*2048 + l*32)      = oT0;
    *(f32x4_t*)(lds + w2*2048 + l*32 + 16) = oT1;
    ((float*)(lds + 16384))[w2*64 + l] = lsum;
    __syncthreads();
    if (gi == 0) {
        const int pw = w2 + 4;
        const f32x4_t b0 = *(const f32x4_t*)(lds + pw*2048 + l*32);
        const f32x4_t b1 = *(const f32x4_t*)(lds + pw*2048 + l*32 + 16);
        const float lp = ((const float*)(lds + 16384))[pw*64 + l];
        oT0 += b0; oT1 += b1;
        lsum += lp;
        lsum += __shfl_xor(lsum, 16);
        lsum += __shfl_xor(lsum, 32);
        const float inv = 1.0f / fmaxf(lsum, 1e-37f);
        float* op = o + (size_t)qa * 256 + head*32;
        float4 v0 = {oT0[0]*inv, oT0[1]*inv, oT0[2]*inv, oT0[3]*inv};
        float4 v1 = {oT1[0]*inv, oT1[1]*inv, oT1[2]*inv, oT1[3]*inv};
        *(float4*)(op + g*4) = v0;
        *(float4*)(op + 16 + g*4) = v1;
    }
}

// ---------------------------------------------------------------------------
extern "C" void kernel_launch(void* const* d_in, const int* in_sizes, int n_in,
                              void* d_out, int out_size, void* d_ws, size_t ws_size,
                              hipStream_t stream)
{
    const float* x     = (const float*)d_in[0];
    const int*   ei    = (const int*)  d_in[1];
    const float* eattr = (const float*)d_in[2];
    const int*   mask  = (const int*)  d_in[3];
    const float* W1   = (const float*)d_in[4];
    const float* b1   = (const float*)d_in[5];
    const float* W2   = (const float*)d_in[6];
    const float* b2   = (const float*)d_in[7];
    const float* ipw  = (const float*)d_in[8];
    const float* ipb  = (const float*)d_in[9];
    const float* ow   = (const float*)d_in[10];
    const float* ob   = (const float*)d_in[11];
    const float* root = (const float*)d_in[12];
    const float* bp   = (const float*)d_in[13];
    const float* ln1g = (const float*)d_in[14];
    const float* ln1b = (const float*)d_in[15];
    const float* ln2g = (const float*)d_in[16];
    const float* ln2b = (const float*)d_in[17];
    const float* linw = (const float*)d_in[18];
    const float* linb = (const float*)d_in[19];
    const int* ei0 = ei;
    const int* ei1 = ei + E_;

    float* ws = (float*)d_ws;
    float* h1    = ws;                              // [E,256]; later attn o
    float* h     = ws + 1048576;                    // [E,256]; later y1
    short* qkvb  = (short*)(ws + 2097152);          // [E,768] bf16 (q pre-scaled)
    float* aggr  = ws + 3670016;                    // [N,256]
    unsigned int* pmask = (unsigned int*)(ws + 4718592);  // [4096][128] bits
    short* vt    = (short*)(ws + 5242896);          // [8][32][4096] bf16
    float* rootT = ws + 5767184;                    // [256][256] f32
    float* o    = h1;
    float* y1   = h;

    dim3 blk(256);
    // prep: mask bits + aggr zero + rootT
    prep_k<<<dim3(2064), blk, 0, stream>>>(mask, pmask, root, rootT, aggr);

    // S1: h1 = leakyrelu(cat(x_i,x_j,eattr) @ W1^T + b1)   [MFMA bf16]
    mgemm_k<1,true,false,false,false><<<dim3(64,4), blk, 0, stream>>>(
        nullptr, W1, b1, nullptr, h1, E_, 256, 768, ei0, ei1, x, eattr, 1.0f);
    // S2: h = h1 @ W2^T + b2   [MFMA bf16]
    mgemm_k<0,false,false,false,false><<<dim3(64,4), blk, 0, stream>>>(
        h1, W2, b2, nullptr, h, E_, 256, 256, nullptr, nullptr, nullptr, nullptr, 1.0f);
    // S3: qkvb = bf16(h @ in_proj_w^T + in_proj_b), q scaled by 1/sqrt(32)
    mgemm_k<0,false,false,false,true><<<dim3(64,12), blk, 0, stream>>>(
        h, ipw, ipb, nullptr, (float*)qkvb, E_, 768, 256, nullptr, nullptr, nullptr, nullptr,
        0.17677669529663687f);
    // V transpose: vt[head][d][key]
    vtrans_k<<<dim3(512), blk, 0, stream>>>(qkvb, vt);
    // S4: MFMA flash attention -> o (f32)
    attn_k<<<dim3(512), dim3(512), 0, stream>>>(qkvb, vt, pmask, o);
    // S5: msg = o @ out_w^T + out_b, scatter-add to aggr   [MFMA bf16]
    mgemm_k<0,false,true,false,false><<<dim3(64,4), blk, 0, stream>>>(
        o, ow, ob, nullptr, aggr, E_, 256, 256, nullptr, ei1, nullptr, nullptr, 1.0f);
    // S6+LN1 fused: y1 = LN1(x @ root + aggr + bias_p)
    rgln_k<<<dim3(32), blk, 0, stream>>>(x, rootT, bp, aggr, ln1g, ln1b, y1);
    // F2+LN2 fused: out = LN2(y1 + y1 @ lin_w^T + lin_b)
    rgln_k<<<dim3(32), blk, 0, stream>>>(y1, linw, linb, y1, ln2g, ln2b, (float*)d_out);
}

// Round 12
// 124.752 us; speedup vs baseline: 1.1314x; 1.1314x over previous
//
#include <hip/hip_runtime.h>
#include <hip/hip_bf16.h>
#include <cstdint>

#define D_   256
#define E_   4096
#define NN_  2048

typedef float f32x4_t __attribute__((ext_vector_type(4)));
typedef short bf16x8_t __attribute__((ext_vector_type(8)));

__device__ inline short f2bf(float f) {
    union { float fv; unsigned u; } v; v.fv = f;
    unsigned r = v.u + 0x7fffu + ((v.u >> 16) & 1u);
    return (short)(r >> 16);
}

__device__ inline unsigned cvtpk_bf16(float lo, float hi) {
    unsigned r;
    asm("v_cvt_pk_bf16_f32 %0, %1, %2" : "=v"(r) : "v"(lo), "v"(hi));
    return r;
}

// ---------------------------------------------------------------------------
// bf16 MFMA GEMM (validated r7/r8/r10): C = epi(A @ Bm^T + bias), inline
// f32->bf16 staging, 64x64 tile, 4 waves, BK=32, dbuf, 1 barrier per K-step.
// ---------------------------------------------------------------------------
template<int ACT, bool GATHER, bool SCATTER, bool HASADD, bool OBF16>
__global__ __launch_bounds__(256)
void mgemm_k(const float* __restrict__ A, const float* __restrict__ Bm,
             const float* __restrict__ bias, const float* __restrict__ addsrc,
             float* __restrict__ C, int M, int N, int K,
             const int* __restrict__ ei0, const int* __restrict__ ei1,
             const float* __restrict__ x, const float* __restrict__ eattr,
             float qsc)
{
    __shared__ char lds[16384];
    const int tid = threadIdx.x;
    const int w = tid >> 6, l = tid & 63;
    const int g = l >> 4, ln = l & 15;
    const int wr = w >> 1, wc = w & 1;
    const int m0 = blockIdx.x * 64, n0 = blockIdx.y * 64;

    const int srow = tid >> 2;
    const int sck  = (tid & 3) * 8;
    const int sswz = (srow & 7) << 4;
    int gi1 = 0, gi0 = 0;
    if (GATHER) { gi1 = ei1[m0 + srow]; gi0 = ei0[m0 + srow]; }

    f32x4_t acc[2][2];
    #pragma unroll
    for (int m = 0; m < 2; m++)
        #pragma unroll
        for (int n = 0; n < 2; n++)
            acc[m][n] = f32x4_t{0.f, 0.f, 0.f, 0.f};

    const int nt = K >> 5;
    float4 ga0, ga1, gb0, gb1;

    auto loadG = [&](int kk) {
        const int cb = kk + sck;
        const float* src;
        if (GATHER) {
            if (cb < 256)      src = x + (size_t)gi1 * 256 + cb;
            else if (cb < 512) src = x + (size_t)gi0 * 256 + (cb - 256);
            else               src = eattr + (size_t)(m0 + srow) * 256 + (cb - 512);
        } else {
            src = A + (size_t)(m0 + srow) * K + cb;
        }
        ga0 = *(const float4*)src;
        ga1 = *(const float4*)(src + 4);
        const float* bsrc = Bm + (size_t)(n0 + srow) * K + cb;
        gb0 = *(const float4*)bsrc;
        gb1 = *(const float4*)(bsrc + 4);
    };
    auto writeS = [&](int buf) {
        uint4 pa, pb;
        pa.x = cvtpk_bf16(ga0.x, ga0.y); pa.y = cvtpk_bf16(ga0.z, ga0.w);
        pa.z = cvtpk_bf16(ga1.x, ga1.y); pa.w = cvtpk_bf16(ga1.z, ga1.w);
        pb.x = cvtpk_bf16(gb0.x, gb0.y); pb.y = cvtpk_bf16(gb0.z, gb0.w);
        pb.z = cvtpk_bf16(gb1.x, gb1.y); pb.w = cvtpk_bf16(gb1.z, gb1.w);
        const int off = (srow*64 + sck*2) ^ sswz;
        *(uint4*)(lds + buf*4096 + off) = pa;
        *(uint4*)(lds + 8192 + buf*4096 + off) = pb;
    };

    loadG(0);
    writeS(0);
    __syncthreads();
    int cur = 0;
    for (int t = 0; t < nt; ++t) {
        if (t + 1 < nt) loadG((t + 1) << 5);
        bf16x8_t af[2], bfr[2];
        #pragma unroll
        for (int m = 0; m < 2; m++) {
            const int row = wr*32 + m*16 + ln;
            af[m] = *(const bf16x8_t*)(lds + cur*4096 + ((row*64 + g*16) ^ ((row&7)<<4)));
        }
        #pragma unroll
        for (int n = 0; n < 2; n++) {
            const int row = wc*32 + n*16 + ln;
            bfr[n] = *(const bf16x8_t*)(lds + 8192 + cur*4096 + ((row*64 + g*16) ^ ((row&7)<<4)));
        }
        #pragma unroll
        for (int m = 0; m < 2; m++)
            #pragma unroll
            for (int n = 0; n < 2; n++)
                acc[m][n] = __builtin_amdgcn_mfma_f32_16x16x32_bf16(af[m], bfr[n], acc[m][n], 0, 0, 0);
        if (t + 1 < nt) writeS(cur ^ 1);
        __syncthreads();
        cur ^= 1;
    }

    #pragma unroll
    for (int m = 0; m < 2; m++) {
        #pragma unroll
        for (int n = 0; n < 2; n++) {
            const int col = n0 + wc*32 + n*16 + ln;
            const float bv = bias[col];
            #pragma unroll
            for (int r = 0; r < 4; r++) {
                const int row = m0 + wr*32 + m*16 + g*4 + r;
                float v = acc[m][n][r] + bv;
                if (ACT == 1) v = v > 0.f ? v : 0.2f * v;
                if (HASADD) v += addsrc[(size_t)row * N + col];
                if (SCATTER) {
                    atomicAdd(&C[(size_t)ei1[row] * 256 + col], v);
                } else if (OBF16) {
                    ((short*)C)[(size_t)row * N + col] = f2bf((col < 256) ? v * qsc : v);
                } else {
                    C[(size_t)row * N + col] = v;
                }
            }
        }
    }
}

// ---------------------------------------------------------------------------
// Prep: mask bit-pack (int32 0/1 layout, established r1->r2 A/B) + aggr zero
// + root transpose, one kernel. Blocks 0..2047: pack+zero; 2048..2063: rootT.
// ---------------------------------------------------------------------------
__global__ __launch_bounds__(256)
void prep_k(const int* __restrict__ mraw, unsigned int* __restrict__ pm,
            const float* __restrict__ root, float* __restrict__ rootT,
            float* __restrict__ aggr)
{
    __shared__ float T[64][65];
    const int bid = blockIdx.x;
    if (bid < 2048) {
        const int t = bid * 256 + threadIdx.x;   // 0 .. 524287
        aggr[t] = 0.f;
        const int row = t >> 7, wb = t & 127;
        unsigned int bits = 0;
        const uint4* p = (const uint4*)(mraw + (size_t)row * 4096 + wb * 32);
        #pragma unroll
        for (int g = 0; g < 8; g++) {
            const uint4 v = p[g];
            if (v.x) bits |= 1u << (g*4+0);
            if (v.y) bits |= 1u << (g*4+1);
            if (v.z) bits |= 1u << (g*4+2);
            if (v.w) bits |= 1u << (g*4+3);
        }
        pm[t] = bits;
    } else {
        const int bt = bid - 2048;
        const int m0 = (bt >> 2) * 64, n0 = (bt & 3) * 64;
        const int r = threadIdx.x >> 6, c = threadIdx.x & 63;
        #pragma unroll
        for (int i = 0; i < 16; i++)
            T[r + i*4][c] = root[(size_t)(m0 + r + i*4) * 256 + n0 + c];
        __syncthreads();
        #pragma unroll
        for (int i = 0; i < 16; i++)
            rootT[(size_t)(n0 + r + i*4) * 256 + m0 + c] = T[c][r + i*4];
    }
}

// ---------------------------------------------------------------------------
// V pre-transpose: vt[head][d=32][key=4096] bf16 from qkv V-part.
// ---------------------------------------------------------------------------
__global__ __launch_bounds__(256)
void vtrans_k(const short* __restrict__ qkvb, short* __restrict__ vt)
{
    __shared__ short Ts[64][40];
    const int head = blockIdx.x >> 6;
    const int k0 = (blockIdx.x & 63) * 64;
    const int tid = threadIdx.x;
    const int skey = tid >> 2, sc = tid & 3;
    const bf16x8_t v = *(const bf16x8_t*)(qkvb + (size_t)(k0 + skey)*768 + 512 + head*32 + sc*8);
    *(bf16x8_t*)(&Ts[skey][sc*8]) = v;
    __syncthreads();
    const int sd = tid >> 3, skc = tid & 7;
    short outv[8];
    #pragma unroll
    for (int j = 0; j < 8; j++) outv[j] = Ts[skc*8 + j][sd];
    *(bf16x8_t*)(vt + (size_t)head*131072 + (size_t)sd*4096 + k0 + skc*8) = *(bf16x8_t*)outv;
}

// ---------------------------------------------------------------------------
// MFMA bf16 flash attention (round-8 structure + setprio, validated 57.6 us,
// FETCH 18.5 MB): swapped QK^T + fixed-shift softmax + in-block split-K x2
// strided; 512 thr; dbuf K/V; additive merge. NEW: mask words prefetched one
// tile ahead (register-rotated) so the global load is off the critical path.
// DO NOT widen split-K: x4 (r9) and range-split (r5) collapsed L2.
// ---------------------------------------------------------------------------
__global__ __launch_bounds__(512, 4)
void attn_k(const short* __restrict__ qkvb, const short* __restrict__ vt,
            const unsigned int* __restrict__ pmask, float* __restrict__ o)
{
    __shared__ char lds[49152];
    const int tid = threadIdx.x;
    const int w2 = tid >> 6, l = tid & 63;
    const int g = l >> 4, ln = l & 15;
    const int gi = w2 >> 2, wq = w2 & 3;
    const int head = blockIdx.x >> 6;
    const int q0 = (blockIdx.x & 63) * 64;
    const int qa = q0 + wq * 16 + ln;

    const bf16x8_t qf = *(const bf16x8_t*)(qkvb + (size_t)qa*768 + head*32 + g*8);

    f32x4_t oT0 = {0.f,0.f,0.f,0.f};
    f32x4_t oT1 = {0.f,0.f,0.f,0.f};
    float lsum = 0.f;

    const int st = tid & 255;
    const int skey = st >> 2, sc = st & 3;
    const int sd = st >> 3, skc = st & 7;
    const short* kgp = qkvb + 256 + head*32 + sc*8;
    const short* vgp = vt + (size_t)head*131072 + (size_t)sd*4096 + skc*8;
    char* Kg = lds + gi*8192;
    char* Vg = lds + 16384 + gi*8192;
    char* Pw = lds + 32768 + w2*2048;
    const unsigned int* mrow = pmask + (size_t)qa*128;
    const int kswz = (skey & 7) << 4, vswz = (sd & 7) << 4;
    const int pswz = (ln & 7) << 4;

    uint2 mwc;
    {   // stage this group's first tile (tt = gi) -> buf 0; preload its mask
        const int k0 = gi * 64;
        const bf16x8_t kv = *(const bf16x8_t*)(kgp + (size_t)(k0 + skey)*768);
        *(bf16x8_t*)(Kg + ((skey*64 + sc*16) ^ kswz)) = kv;
        const bf16x8_t vv = *(const bf16x8_t*)(vgp + k0);
        *(bf16x8_t*)(Vg + ((sd*128 + skc*16) ^ vswz)) = vv;
        mwc = *(const uint2*)(mrow + gi*2);
    }

    for (int i = 0; i < 32; ++i) {
        __syncthreads();
        const int cur = i & 1;
        const int tt = 2*i + gi;
        uint2 mwn;
        if (i < 31) {   // prefetch this group's next tile (tt+2) + its mask
            const int k0n = (tt + 2) * 64;
            const bf16x8_t kv = *(const bf16x8_t*)(kgp + (size_t)(k0n + skey)*768);
            *(bf16x8_t*)(Kg + (cur^1)*4096 + ((skey*64 + sc*16) ^ kswz)) = kv;
            const bf16x8_t vv = *(const bf16x8_t*)(vgp + k0n);
            *(bf16x8_t*)(Vg + (cur^1)*4096 + ((sd*128 + skc*16) ^ vswz)) = vv;
            mwn = *(const uint2*)(mrow + (tt + 2)*2);
        }
        char* Kb = Kg + cur*4096;
        char* Vb = Vg + cur*4096;

        // S^T = mfma(K, Q): col=q=ln, rows = keys kt*16+g*4+r
        f32x4_t s[4];
        __builtin_amdgcn_s_setprio(1);
        #pragma unroll
        for (int kt = 0; kt < 4; kt++) {
            const int key = kt*16 + ln;
            const bf16x8_t kf = *(const bf16x8_t*)(Kb + ((key*64 + g*16) ^ ((key & 7) << 4)));
            f32x4_t z = {0.f,0.f,0.f,0.f};
            s[kt] = __builtin_amdgcn_mfma_f32_16x16x32_bf16(kf, qf, z, 0, 0, 0);
        }
        __builtin_amdgcn_s_setprio(0);

        // fixed-shift masked exp; lsum; pack P -> LDS
        #pragma unroll
        for (int kt = 0; kt < 4; kt++) {
            const unsigned word = (kt < 2) ? mwc.x : mwc.y;
            float p[4];
            #pragma unroll
            for (int r = 0; r < 4; r++) {
                const float e = __expf(s[kt][r] - 12.0f);
                p[r] = ((word >> ((kt & 1)*16 + g*4 + r)) & 1u) ? e : 0.f;
            }
            lsum += (p[0] + p[1]) + (p[2] + p[3]);
            uint2 pk;
            pk.x = cvtpk_bf16(p[0], p[1]);
            pk.y = cvtpk_bf16(p[2], p[3]);
            *(uint2*)(Pw + ((ln*128 + kt*32 + g*8) ^ pswz)) = pk;
        }

        // PV: O^T += Vt . P
        __builtin_amdgcn_s_setprio(1);
        #pragma unroll
        for (int kh = 0; kh < 2; kh++) {
            const bf16x8_t pf = *(const bf16x8_t*)(Pw + ((ln*128 + kh*64 + g*16) ^ pswz));
            const bf16x8_t vf0 = *(const bf16x8_t*)(Vb + ((ln*128 + kh*64 + g*16) ^ pswz));
            const bf16x8_t vf1 = *(const bf16x8_t*)(Vb + (((16+ln)*128 + kh*64 + g*16) ^ pswz));
            oT0 = __builtin_amdgcn_mfma_f32_16x16x32_bf16(vf0, pf, oT0, 0, 0, 0);
            oT1 = __builtin_amdgcn_mfma_f32_16x16x32_bf16(vf1, pf, oT1, 0, 0, 0);
        }
        __builtin_amdgcn_s_setprio(0);
        mwc = mwn;
    }

    // ---- additive merge of the two key-group partials ----
    __syncthreads();
    *(f32x4_t*)(lds + w2*2048 + l*32)      = oT0;
    *(f32x4_t*)(lds + w2*2048 + l*32 + 16) = oT1;
    ((float*)(lds + 16384))[w2*64 + l] = lsum;
    __syncthreads();
    if (gi == 0) {
        const int pw = w2 + 4;
        const f32x4_t b0 = *(const f32x4_t*)(lds + pw*2048 + l*32);
        const f32x4_t b1 = *(const f32x4_t*)(lds + pw*2048 + l*32 + 16);
        const float lp = ((const float*)(lds + 16384))[pw*64 + l];
        oT0 += b0; oT1 += b1;
        lsum += lp;
        lsum += __shfl_xor(lsum, 16);
        lsum += __shfl_xor(lsum, 32);
        const float inv = 1.0f / fmaxf(lsum, 1e-37f);
        float* op = o + (size_t)qa * 256 + head*32;
        float4 v0 = {oT0[0]*inv, oT0[1]*inv, oT0[2]*inv, oT0[3]*inv};
        float4 v1 = {oT1[0]*inv, oT1[1]*inv, oT1[2]*inv, oT1[3]*inv};
        *(float4*)(op + g*4) = v0;
        *(float4*)(op + 16 + g*4) = v1;
    }
}

// ---------------------------------------------------------------------------
// LayerNorm over 256 dims, one block per row.
// ---------------------------------------------------------------------------
__global__ __launch_bounds__(256)
void ln_k(const float* __restrict__ in, const float* __restrict__ g,
          const float* __restrict__ b, float* __restrict__ out)
{
    const int n = blockIdx.x, t = threadIdx.x;
    const float v = in[(size_t)n * 256 + t];
    float s1 = v, s2 = v * v;
    #pragma unroll
    for (int off = 32; off > 0; off >>= 1) {
        s1 += __shfl_xor(s1, off);
        s2 += __shfl_xor(s2, off);
    }
    __shared__ float r1[4], r2[4];
    const int wv = t >> 6;
    if ((t & 63) == 0) { r1[wv] = s1; r2[wv] = s2; }
    __syncthreads();
    const float t1 = r1[0] + r1[1] + r1[2] + r1[3];
    const float t2 = r2[0] + r2[1] + r2[2] + r2[3];
    const float mu  = t1 * (1.0f / 256.0f);
    const float var = t2 * (1.0f / 256.0f) - mu * mu;
    const float rs  = rsqrtf(var + 1e-5f);
    out[(size_t)n * 256 + t] = (v - mu) * rs * g[t] + b[t];
}

// ---------------------------------------------------------------------------
extern "C" void kernel_launch(void* const* d_in, const int* in_sizes, int n_in,
                              void* d_out, int out_size, void* d_ws, size_t ws_size,
                              hipStream_t stream)
{
    const float* x     = (const float*)d_in[0];
    const int*   ei    = (const int*)  d_in[1];
    const float* eattr = (const float*)d_in[2];
    const int*   mask  = (const int*)  d_in[3];
    const float* W1   = (const float*)d_in[4];
    const float* b1   = (const float*)d_in[5];
    const float* W2   = (const float*)d_in[6];
    const float* b2   = (const float*)d_in[7];
    const float* ipw  = (const float*)d_in[8];
    const float* ipb  = (const float*)d_in[9];
    const float* ow   = (const float*)d_in[10];
    const float* ob   = (const float*)d_in[11];
    const float* root = (const float*)d_in[12];
    const float* bp   = (const float*)d_in[13];
    const float* ln1g = (const float*)d_in[14];
    const float* ln1b = (const float*)d_in[15];
    const float* ln2g = (const float*)d_in[16];
    const float* ln2b = (const float*)d_in[17];
    const float* linw = (const float*)d_in[18];
    const float* linb = (const float*)d_in[19];
    const int* ei0 = ei;
    const int* ei1 = ei + E_;

    float* ws = (float*)d_ws;
    float* h1    = ws;                              // [E,256]; later attn o; later z
    float* h     = ws + 1048576;                    // [E,256]; later y1
    short* qkvb  = (short*)(ws + 2097152);          // [E,768] bf16 (q pre-scaled)
    float* aggr  = ws + 3670016;                    // [N,256]
    float* outb  = ws + 4194304;                    // [N,256]
    unsigned int* pmask = (unsigned int*)(ws + 4718592);  // [4096][128] bits
    short* vt    = (short*)(ws + 5242896);          // [8][32][4096] bf16
    float* rootT = ws + 5767184;                    // [256][256] f32
    float* o    = h1;
    float* y1   = h;
    float* z    = h1;

    dim3 blk(256);
    // prep: mask bits + aggr zero + rootT
    prep_k<<<dim3(2064), blk, 0, stream>>>(mask, pmask, root, rootT, aggr);

    // S1: h1 = leakyrelu(cat(x_i,x_j,eattr) @ W1^T + b1)   [MFMA bf16]
    mgemm_k<1,true,false,false,false><<<dim3(64,4), blk, 0, stream>>>(
        nullptr, W1, b1, nullptr, h1, E_, 256, 768, ei0, ei1, x, eattr, 1.0f);
    // S2: h = h1 @ W2^T + b2   [MFMA bf16]
    mgemm_k<0,false,false,false,false><<<dim3(64,4), blk, 0, stream>>>(
        h1, W2, b2, nullptr, h, E_, 256, 256, nullptr, nullptr, nullptr, nullptr, 1.0f);
    // S3: qkvb = bf16(h @ in_proj_w^T + in_proj_b), q scaled by 1/sqrt(32)
    mgemm_k<0,false,false,false,true><<<dim3(64,12), blk, 0, stream>>>(
        h, ipw, ipb, nullptr, (float*)qkvb, E_, 768, 256, nullptr, nullptr, nullptr, nullptr,
        0.17677669529663687f);
    // V transpose: vt[head][d][key]
    vtrans_k<<<dim3(512), blk, 0, stream>>>(qkvb, vt);
    // S4: MFMA flash attention -> o (f32)
    attn_k<<<dim3(512), dim3(512), 0, stream>>>(qkvb, vt, pmask, o);
    // S5: msg = o @ out_w^T + out_b, scatter-add to aggr   [MFMA bf16]
    mgemm_k<0,false,true,false,false><<<dim3(64,4), blk, 0, stream>>>(
        o, ow, ob, nullptr, aggr, E_, 256, 256, nullptr, ei1, nullptr, nullptr, 1.0f);
    // S6: out = x @ root + aggr + bias_p   [MFMA bf16 + exact f32 add]
    mgemm_k<0,false,false,true,false><<<dim3(32,4), blk, 0, stream>>>(
        x, rootT, bp, aggr, outb, NN_, 256, 256, nullptr, nullptr, nullptr, nullptr, 1.0f);
    // LN1
    ln_k<<<dim3(2048), blk, 0, stream>>>(outb, ln1g, ln1b, y1);
    // F2: z = y1 + y1 @ lin_w^T + lin_b   [MFMA bf16 + exact f32 residual]
    mgemm_k<0,false,false,true,false><<<dim3(32,4), blk, 0, stream>>>(
        y1, linw, linb, y1, z, NN_, 256, 256, nullptr, nullptr, nullptr, nullptr, 1.0f);
    // LN2 -> out
    ln_k<<<dim3(2048), blk, 0, stream>>>(z, ln2g, ln2b, (float*)d_out);
}